// Round 18
// baseline (64.099 us; speedup 1.0000x reference)
//
#include <hip/hip_runtime.h>
#include <math.h>

#define IMG 256
#define N_ANG 360
#define N_DET 256
// VOX = 2.0

#define NHA 181                    // H angles
#define KT 4                       // H k-window splits (64 samples each)
#define NH_BLOCKS (NHA * KT)       // 724
#define NV_BLOCKS (179 * 64)       // 179 V-angles x 64 detector-groups of 4

struct W9 { float w[9]; };
struct AngTab { double c, sn; float cf, snf; float pad0, pad1; };   // 32 B

typedef _Float16 h2 __attribute__((ext_vector_type(2)));

#if __has_builtin(__builtin_amdgcn_fdot2)
__device__ __forceinline__ float fdot2(h2 a, h2 b, float c) {
    return __builtin_amdgcn_fdot2(a, b, c, false);
}
#else
__device__ __forceinline__ float fdot2(h2 a, h2 b, float c) {
    return c + (float)a[0] * (float)b[0] + (float)a[1] * (float)b[1];
}
#endif

__device__ __forceinline__ h2 as_h2(unsigned u) { return __builtin_bit_cast(h2, u); }
__device__ __forceinline__ unsigned pack2(float a, float b) {
    h2 v = { (_Float16)a, (_Float16)b };        // RTN casts (unbiased)
    return __builtin_bit_cast(unsigned, v);
}

__device__ __forceinline__ int refl(int i, int L) {
    if (i < 0) i = -i;
    if (i >= L) i = 2 * (L - 1) - i;
    return i;
}

template <typename P>
__device__ __forceinline__ int lastTrue(P p) {     // pred true-set is a prefix of [0,255]
    if (!p(0)) return -1;
    if (p(255)) return 255;
    int lo = 0, hi = 255;
    while (lo < hi) { int m = (lo + hi + 1) >> 1; if (p(m)) lo = m; else hi = m - 1; }
    return lo;
}
template <typename P>
__device__ __forceinline__ int firstTrue(P p) {    // pred true-set is a suffix of [0,255]
    if (!p(255)) return 256;
    if (p(0)) return 0;
    int lo = 0, hi = 255;
    while (lo < hi) { int m = (lo + hi) >> 1; if (p(m)) hi = m; else lo = m + 1; }
    return lo;
}

// Fused blurs -> pre-paired 16B/px image + per-angle tables + exact f64
// interval & f32 ray origin for ALL 360x256 rays (<=2 rays per thread).
__global__ void blurpix_k(const float* __restrict__ img, const float* __restrict__ att,
                          uint4* __restrict__ pix2, AngTab* __restrict__ tab,
                          int2* __restrict__ ivl, float2* __restrict__ pos0,
                          W9 wi, W9 wa) {
    int x = threadIdx.x, y = blockIdx.x;
    int gid = y * IMG + x;
    if (gid < N_ANG) {
        double th = M_PI * (double)gid / 360.0;
        double c = cos(th), sn = sin(th);
        AngTab tb;
        tb.c = c; tb.sn = sn; tb.cf = (float)c; tb.snf = (float)sn;
        tb.pad0 = 0.f; tb.pad1 = 0.f;
        tab[gid] = tb;
    }
    float v[4];
    #pragma unroll
    for (int m = 0; m < 4; ++m) {
        const float* src = ((m & 1) ? att : img) + (m >> 1) * IMG * IMG;
        const float* w = (m & 1) ? wa.w : wi.w;
        const int r = (m & 1) ? 4 : 2;
        float acc = 0.f;
        for (int dy = -r; dy <= r; ++dy) {
            const float* rowp = src + refl(y + dy, IMG) * IMG;
            float ra = 0.f;
            for (int dx = -r; dx <= r; ++dx) ra += w[dx + r] * rowp[refl(x + dx, IMG)];
            acc += w[dy + r] * ra;
        }
        v[m] = acc * ((m & 1) ? 0.01f : 1.0f);
    }
    __shared__ float4 row[IMG];
    row[x] = make_float4(v[0], v[1], v[2], v[3]);
    __syncthreads();
    float4 rn = row[min(x + 1, IMG - 1)];
    uint4 o;
    o.x = pack2(v[0], rn.x);     // img_b0 {left,right}
    o.y = pack2(v[1], rn.y);     // att_b0
    o.z = pack2(v[2], rn.z);     // img_b1
    o.w = pack2(v[3], rn.w);     // att_b1
    pix2[gid] = o;

    // Exact interval tables for all rays (a in [0,360), d in [0,256)).
    for (int ray = gid; ray < N_ANG * N_DET; ray += IMG * IMG) {
        int a = ray >> 8, d = ray & 255;
        double th = M_PI * (double)a / 360.0;
        double c = cos(th), sn = sin(th);
        double rr = (double)(2 * d - 255);
        double rc = __dmul_rn(rr, c), rs = __dmul_rn(rr, sn);
        auto evIx = [&](int k) -> double {
            double ss = (double)(2 * k - 255);
            return __dadd_rn(__dmul_rn(__dsub_rn(rc, __dmul_rn(ss, sn)), 0.5), 127.5);
        };
        auto evIy = [&](int k) -> double {
            double ss = (double)(2 * k - 255);
            return __dadd_rn(__dmul_rn(__dadd_rn(rs, __dmul_rn(ss, c)), 0.5), 127.5);
        };
        // ix non-increasing in k (slope -sn, sn>=0 for a in [0,360)); iy slope = +c.
        int khiA = lastTrue([&](int k) { return evIx(k) >= 0.0; });
        int kloA = firstTrue([&](int k) { return evIx(k) <= 255.0; });
        int kloB, khiB;
        if (c > 0.0) {
            kloB = firstTrue([&](int k) { return evIy(k) >= 0.0; });
            khiB = lastTrue([&](int k) { return evIy(k) <= 255.0; });
        } else {
            khiB = lastTrue([&](int k) { return evIy(k) >= 0.0; });
            kloB = firstTrue([&](int k) { return evIy(k) <= 255.0; });
        }
        ivl[ray] = make_int2(max(kloA, kloB), min(khiA, khiB));
        pos0[ray] = make_float2((float)evIx(128), (float)evIy(128));
    }
}

// Two 16B row-loads + 8 dot2 per sample — zero perms (pairs pre-stored).
__device__ __forceinline__ void tap_acc(const uint4* __restrict__ pix2,
                                        int i0, int j0,
                                        float w00, float w01, float w10, float w11,
                                        float4& acc) {
    h2 wt = { (_Float16)w00, (_Float16)w01 };
    h2 wb = { (_Float16)w10, (_Float16)w11 };
    const uint4* p0 = pix2 + (i0 << 8) + j0;
    uint4 T = p0[0];            // row i0:   4 maps x {left,right}
    uint4 B = p0[IMG];          // row i0+1
    acc.x = fdot2(as_h2(T.x), wt, acc.x);
    acc.x = fdot2(as_h2(B.x), wb, acc.x);
    acc.y = fdot2(as_h2(T.y), wt, acc.y);
    acc.y = fdot2(as_h2(B.y), wb, acc.y);
    acc.z = fdot2(as_h2(T.z), wt, acc.z);
    acc.z = fdot2(as_h2(B.z), wb, acc.z);
    acc.w = fdot2(as_h2(T.w), wt, acc.w);
    acc.w = fdot2(as_h2(B.w), wb, acc.w);
}

// Merged projection, 256-thread blocks, f64-free (intervals precomputed).
// 724 H blocks (angle x kt): thread = detector, 64-sample window, direct store.
// 11456 V blocks (angle x 4-det group): wave = ray, lane = sample; interval mask.
__global__ __launch_bounds__(256) void proj_k(const uint4* __restrict__ pix2,
                                              const AngTab* __restrict__ tab,
                                              const int2* __restrict__ ivl,
                                              const float2* __restrict__ pos0,
                                              float4* __restrict__ part4H,
                                              float4* __restrict__ part4V) {
    int t = threadIdx.x;
    int bx = blockIdx.x;

    if (bx < NH_BLOCKS) {
        // ---- H-mode: lanes = detectors ----
        int aidx = bx >> 2, kt = bx & 3;
        int d = t;
        int a = (aidx <= 90) ? aidx : aidx + 179;
        AngTab tb = tab[a];
        int ray = a * N_DET + d;
        int2 iv = ivl[ray];
        float2 p0 = pos0[ray];

        int lo = max(iv.x, kt * 64), hi = min(iv.y, kt * 64 + 63);
        if (lo > hi) { lo = 0; hi = -1; }                // canonical empty

        int jl = (hi >= lo) ? lo : 0x7fffffff;           // wave hull
        int jh = (hi >= lo) ? hi : (-0x7fffffff - 1);
        #pragma unroll
        for (int off = 32; off; off >>= 1) {
            jl = min(jl, __shfl_xor(jl, off));
            jh = max(jh, __shfl_xor(jh, off));
        }

        float dxf = -tb.snf, dyf = tb.cf;

        float4 acc = make_float4(0.f, 0.f, 0.f, 0.f);
        for (int kb = jl; kb <= jh; kb += 4) {
            #pragma unroll
            for (int u = 0; u < 4; ++u) {
                int k = kb + u;
                float kf = (float)(k - 128);
                float ixf = fmaf(kf, dxf, p0.x);
                float iyf = fmaf(kf, dyf, p0.y);
                float m = (k >= lo && k <= hi) ? 2.0f : 0.0f;    // valid * VOX
                int j0 = (int)ixf; j0 = min(max(j0, 0), 254);
                int i0 = (int)iyf; i0 = min(max(i0, 0), 254);
                float fx = ixf - (float)j0;
                float fy = iyf - (float)i0;
                float gxm = (1.f - fx) * m, fxm = fx * m;
                float gy = 1.f - fy;
                tap_acc(pix2, i0, j0, gy * gxm, gy * fxm, fy * gxm, fy * fxm, acc);
            }
        }
        part4H[(kt * NHA + aidx) * N_DET + d] = acc;     // direct store
    } else {
        // ---- V-mode: wave = ray, lane = sample; interval mask, no f64 ----
        int idx = bx - NH_BLOCKS;
        int a = 91 + (idx >> 6);
        int dgrp = idx & 63;
        int lane = t & 63, w = t >> 6;
        int d = dgrp * 4 + w;
        AngTab tb = tab[a];
        int ray = a * N_DET + d;
        int2 iv = ivl[ray];                              // wave-uniform
        float2 p0 = pos0[ray];
        float dxf = -tb.snf, dyf = tb.cf;

        float4 acc = make_float4(0.f, 0.f, 0.f, 0.f);
        #pragma unroll
        for (int j = 0; j < 4; ++j) {
            int k = j * 64 + lane;
            if (j * 64 + 63 < iv.x || j * 64 > iv.y) continue;   // window disjoint
            float kf = (float)(k - 128);
            float ixf = fmaf(kf, dxf, p0.x);
            float iyf = fmaf(kf, dyf, p0.y);
            float m = (k >= iv.x && k <= iv.y) ? 2.0f : 0.0f;    // valid * VOX
            int j0 = (int)ixf; j0 = min(max(j0, 0), 254);
            int i0 = (int)iyf; i0 = min(max(i0, 0), 254);
            float fx = ixf - (float)j0;
            float fy = iyf - (float)i0;
            float gxm = (1.f - fx) * m, fxm = fx * m;
            float gy = 1.f - fy;
            tap_acc(pix2, i0, j0, gy * gxm, gy * fxm, fy * gxm, fy * fxm, acc);
        }

        #pragma unroll
        for (int off = 32; off; off >>= 1) {
            acc.x += __shfl_xor(acc.x, off);
            acc.y += __shfl_xor(acc.y, off);
            acc.z += __shfl_xor(acc.z, off);
            acc.w += __shfl_xor(acc.w, off);
        }
        if (lane == 0) part4V[(a - 91) * N_DET + d] = acc;   // sole writer
    }
}

// All angles: kt-sum (H) or direct read (V) + attenuation + detector blur +
// transpose to out[b][det][ang].
__global__ __launch_bounds__(256) void finish_k(const float4* __restrict__ part4H,
                                                const float4* __restrict__ part4V,
                                                float* __restrict__ out, W9 wt) {
    int d = threadIdx.x;
    int b = blockIdx.x / N_ANG;
    int a = blockIdx.x % N_ANG;
    float4 s;
    if (a <= 90 || a >= 270) {
        int aidx = (a <= 90) ? a : a - 179;
        s = make_float4(0.f, 0.f, 0.f, 0.f);
        #pragma unroll
        for (int kt = 0; kt < KT; ++kt) {
            float4 q = part4H[(kt * NHA + aidx) * N_DET + d];
            s.x += q.x; s.y += q.y; s.z += q.z; s.w += q.w;
        }
    } else {
        s = part4V[(a - 91) * N_DET + d];
    }
    float si = b ? s.z : s.x;
    float sa = b ? s.w : s.y;
    __shared__ float vb[N_DET];
    vb[d] = si * expf(-sa * 2.0f);     // * exp(-att_sino * VOX)
    __syncthreads();
    float acc = 0.f;
    #pragma unroll
    for (int i = -2; i <= 2; ++i) acc += wt.w[i + 2] * vb[refl(d + i, N_DET)];
    out[(b * N_DET + d) * N_ANG + a] = acc;
}

static void gauss_w(W9* wt, double sigma, int r) {
    double tmp[9];
    double s = 0.0;
    for (int i = -r; i <= r; ++i) {
        double v = exp(-0.5 * ((double)i / sigma) * ((double)i / sigma));
        tmp[i + r] = v;
        s += v;
    }
    for (int i = 0; i < 9; ++i) wt->w[i] = 0.f;
    for (int i = 0; i < 2 * r + 1; ++i) wt->w[i] = (float)(tmp[i] / s);
}

extern "C" void kernel_launch(void* const* d_in, const int* in_sizes, int n_in,
                              void* d_out, int out_size, void* d_ws, size_t ws_size,
                              hipStream_t stream) {
    const float* img = (const float*)d_in[0];
    const float* att = (const float*)d_in[1];
    float* out = (float*)d_out;

    char* ws = (char*)d_ws;
    AngTab* tab    = (AngTab*)ws;                                  // 16 KiB
    uint4* pix2    = (uint4*)(ws + 16384);                         // 1 MiB
    int2* ivl      = (int2*)(ws + 16384 + (1 << 20));              // 720 KB (1M slot)
    float2* pos0   = (float2*)(ws + 16384 + 2 * (1 << 20));        // 720 KB (1M slot)
    float4* part4H = (float4*)(ws + 16384 + 3 * (1 << 20));        // 2.97 MiB
    float4* part4V = (float4*)(ws + 16384 + 6 * (1 << 20));        // 0.73 MiB
    // total ~6.8 MiB

    double sqrt_log2 = sqrt(log(2.0));
    double sigma_img = 4.0 / (4.0 * sqrt_log2) / 2.0;              // ~0.60056, r=2
    double sigma_att = 4.0 / (2.0 * sqrt_log2) / 2.0;              // ~1.20112, r=4
    W9 wimg, watt;
    gauss_w(&wimg, sigma_img, 2);          // 5-tap at [0..4]
    gauss_w(&watt, sigma_att, 4);          // 9-tap

    blurpix_k<<<IMG, IMG, 0, stream>>>(img, att, pix2, tab, ivl, pos0, wimg, watt);
    proj_k<<<NH_BLOCKS + NV_BLOCKS, 256, 0, stream>>>(pix2, tab, ivl, pos0,
                                                      part4H, part4V);
    finish_k<<<2 * N_ANG, N_DET, 0, stream>>>(part4H, part4V, out, wimg);
}

// Round 19
// 57.972 us; speedup vs baseline: 1.1057x; 1.1057x over previous
//
#include <hip/hip_runtime.h>
#include <math.h>

#define IMG 256
#define N_ANG 360
#define N_DET 256
// VOX = 2.0

#define NH_BLOCKS 181              // 181 H-angles (kc split in-block)
#define NV_BLOCKS (179 * 32)       // 179 V-angles x 32 detector-groups
#define EPS 1e-3f                  // f32-vs-f64 geometry margin (V-mode only)

struct W9 { float w[9]; };
struct AngTab { double c, sn; float cf, snf; float pad0, pad1; };   // 32 B

typedef _Float16 h2 __attribute__((ext_vector_type(2)));

#if __has_builtin(__builtin_amdgcn_fdot2)
__device__ __forceinline__ float fdot2(h2 a, h2 b, float c) {
    return __builtin_amdgcn_fdot2(a, b, c, false);
}
#else
__device__ __forceinline__ float fdot2(h2 a, h2 b, float c) {
    return c + (float)a[0] * (float)b[0] + (float)a[1] * (float)b[1];
}
#endif

__device__ __forceinline__ h2 as_h2(unsigned u) { return __builtin_bit_cast(h2, u); }
__device__ __forceinline__ unsigned pack2(float a, float b) {
    h2 v = { (_Float16)a, (_Float16)b };        // RTN casts (unbiased)
    return __builtin_bit_cast(unsigned, v);
}

__device__ __forceinline__ int refl(int i, int L) {
    if (i < 0) i = -i;
    if (i >= L) i = 2 * (L - 1) - i;
    return i;
}

// Fused blurs -> pre-paired 16B/px image. pix2[i][j] dwords:
//   {img0_j|img0_j+1, att0_j|att0_j+1, img1 pair, att1 pair}  (f16 pairs)
// Right-neighbor values obtained via one LDS row exchange.
// First 360 threads also build the per-angle sin/cos tables.
__global__ void blurpix_k(const float* __restrict__ img, const float* __restrict__ att,
                          uint4* __restrict__ pix2, AngTab* __restrict__ tab,
                          W9 wi, W9 wa) {
    int x = threadIdx.x, y = blockIdx.x;
    int gid = y * IMG + x;
    if (gid < N_ANG) {
        double th = M_PI * (double)gid / 360.0;
        double c = cos(th), sn = sin(th);
        AngTab tb;
        tb.c = c; tb.sn = sn; tb.cf = (float)c; tb.snf = (float)sn;
        tb.pad0 = 0.f; tb.pad1 = 0.f;
        tab[gid] = tb;
    }
    float v[4];
    #pragma unroll
    for (int m = 0; m < 4; ++m) {
        const float* src = ((m & 1) ? att : img) + (m >> 1) * IMG * IMG;
        const float* w = (m & 1) ? wa.w : wi.w;
        const int r = (m & 1) ? 4 : 2;          // true radius per map (unrolled)
        float acc = 0.f;
        for (int dy = -r; dy <= r; ++dy) {
            const float* rowp = src + refl(y + dy, IMG) * IMG;
            float ra = 0.f;
            for (int dx = -r; dx <= r; ++dx) ra += w[dx + r] * rowp[refl(x + dx, IMG)];
            acc += w[dy + r] * ra;
        }
        v[m] = acc * ((m & 1) ? 0.01f : 1.0f);
    }
    __shared__ float4 row[IMG];
    row[x] = make_float4(v[0], v[1], v[2], v[3]);
    __syncthreads();
    float4 rn = row[min(x + 1, IMG - 1)];
    uint4 o;
    o.x = pack2(v[0], rn.x);     // img_b0 {left,right}
    o.y = pack2(v[1], rn.y);     // att_b0
    o.z = pack2(v[2], rn.z);     // img_b1
    o.w = pack2(v[3], rn.w);     // att_b1
    pix2[gid] = o;
}

template <typename P>
__device__ __forceinline__ int lastTrue(P p) {     // pred true-set is a prefix of [0,255]
    if (!p(0)) return -1;
    if (p(255)) return 255;
    int lo = 0, hi = 255;
    while (lo < hi) { int m = (lo + hi + 1) >> 1; if (p(m)) lo = m; else hi = m - 1; }
    return lo;
}
template <typename P>
__device__ __forceinline__ int firstTrue(P p) {    // pred true-set is a suffix of [0,255]
    if (!p(255)) return 256;
    if (p(0)) return 0;
    int lo = 0, hi = 255;
    while (lo < hi) { int m = (lo + hi) >> 1; if (p(m)) hi = m; else lo = m + 1; }
    return lo;
}

// Two 16B row-loads + 8 dot2 per sample — zero perms (pairs pre-stored).
__device__ __forceinline__ void tap_acc(const uint4* __restrict__ pix2,
                                        int i0, int j0,
                                        float w00, float w01, float w10, float w11,
                                        float4& acc) {
    h2 wt = { (_Float16)w00, (_Float16)w01 };
    h2 wb = { (_Float16)w10, (_Float16)w11 };
    const uint4* p0 = pix2 + (i0 << 8) + j0;
    uint4 T = p0[0];            // row i0:   4 maps x {left,right}
    uint4 B = p0[IMG];          // row i0+1
    acc.x = fdot2(as_h2(T.x), wt, acc.x);
    acc.x = fdot2(as_h2(B.x), wb, acc.x);
    acc.y = fdot2(as_h2(T.y), wt, acc.y);
    acc.y = fdot2(as_h2(B.y), wb, acc.y);
    acc.z = fdot2(as_h2(T.z), wt, acc.z);
    acc.z = fdot2(as_h2(B.z), wb, acc.z);
    acc.w = fdot2(as_h2(T.w), wt, acc.w);
    acc.w = fdot2(as_h2(B.w), wb, acc.w);
}

// Merged projection. 181 H blocks (lanes = detectors, exact per-ray interval,
// unroll-4 hull walk, inline finish) + 5728 V blocks (lanes = samples).
__global__ __launch_bounds__(512) void proj_k(const uint4* __restrict__ pix2,
                                              const AngTab* __restrict__ tab,
                                              float4* __restrict__ part4,
                                              float* __restrict__ out, W9 wblur) {
    int t = threadIdx.x;
    int bx = blockIdx.x;

    if (bx < NH_BLOCKS) {
        // ---- H-mode: |sin| <= |cos| (a in [0,90] U [270,359]) ----
        int d = t & 255, kc = t >> 8;
        int a = (bx <= 90) ? bx : bx + 179;
        AngTab tb = tab[a];
        double rr = (double)(2 * d - 255);
        double rc = __dmul_rn(rr, tb.c), rs = __dmul_rn(rr, tb.sn);

        auto evIx = [&](int k) -> double {
            double ss = (double)(2 * k - 255);
            return __dadd_rn(__dmul_rn(__dsub_rn(rc, __dmul_rn(ss, tb.sn)), 0.5), 127.5);
        };
        auto evIy = [&](int k) -> double {
            double ss = (double)(2 * k - 255);
            return __dadd_rn(__dmul_rn(__dadd_rn(rs, __dmul_rn(ss, tb.c)), 0.5), 127.5);
        };
        // ix non-increasing in k (slope -sn, sn>=0 for all a); iy slope = +c.
        int khiA = lastTrue([&](int k) { return evIx(k) >= 0.0; });
        int kloA = firstTrue([&](int k) { return evIx(k) <= 255.0; });
        int kloB, khiB;
        if (tb.c > 0.0) {
            kloB = firstTrue([&](int k) { return evIy(k) >= 0.0; });
            khiB = lastTrue([&](int k) { return evIy(k) <= 255.0; });
        } else {
            khiB = lastTrue([&](int k) { return evIy(k) >= 0.0; });
            kloB = firstTrue([&](int k) { return evIy(k) <= 255.0; });
        }
        int lo = max(kloA, kloB), hi = min(khiA, khiB);
        lo = max(lo, kc * 128); hi = min(hi, kc * 128 + 127);   // this thread's chunk
        if (lo > hi) { lo = 0; hi = -1; }                        // canonical empty

        // wave hull
        int jl = (hi >= lo) ? lo : 0x7fffffff;
        int jh = (hi >= lo) ? hi : (-0x7fffffff - 1);
        #pragma unroll
        for (int off = 32; off; off >>= 1) {
            jl = min(jl, __shfl_xor(jl, off));
            jh = max(jh, __shfl_xor(jh, off));
        }

        float x0f = (float)evIx(128);
        float y0f = (float)evIy(128);
        float dxf = -tb.snf, dyf = tb.cf;

        float4 acc = make_float4(0.f, 0.f, 0.f, 0.f);
        // Unroll-4 hull walk: 4 independent samples per trip -> 8 loads in
        // flight. Overshoot samples are mask-killed (addresses clamped).
        for (int kb = jl; kb <= jh; kb += 4) {
            #pragma unroll
            for (int u = 0; u < 4; ++u) {
                int k = kb + u;
                float kf = (float)(k - 128);
                float ixf = fmaf(kf, dxf, x0f);
                float iyf = fmaf(kf, dyf, y0f);
                float m = (k >= lo && k <= hi) ? 2.0f : 0.0f;    // valid * VOX
                int j0 = (int)ixf; j0 = min(max(j0, 0), 254);
                int i0 = (int)iyf; i0 = min(max(i0, 0), 254);
                float fx = ixf - (float)j0;
                float fy = iyf - (float)i0;
                float gxm = (1.f - fx) * m, fxm = fx * m;
                float gy = 1.f - fy;
                tap_acc(pix2, i0, j0, gy * gxm, gy * fxm, fy * gxm, fy * fxm, acc);
            }
        }

        __shared__ float4 red[512];
        __shared__ float vb[2][N_DET];
        red[t] = acc;
        __syncthreads();
        if (t < 256) {
            float4 u = red[t], v = red[t + 256];
            float si0 = u.x + v.x, sa0 = u.y + v.y;
            float si1 = u.z + v.z, sa1 = u.w + v.w;
            vb[0][t] = si0 * expf(-sa0 * 2.0f);   // * exp(-att_sino * VOX)
            vb[1][t] = si1 * expf(-sa1 * 2.0f);
        }
        __syncthreads();
        if (t < 256) {
            float a0 = 0.f, a1 = 0.f;
            #pragma unroll
            for (int i = -2; i <= 2; ++i) {
                int dd = refl(t + i, N_DET);
                a0 += wblur.w[i + 2] * vb[0][dd];
                a1 += wblur.w[i + 2] * vb[1][dd];
            }
            out[t * N_ANG + a] = a0;                       // b=0
            out[(N_DET + t) * N_ANG + a] = a1;             // b=1
        }
    } else {
        // ---- V-mode: |sin| > |cos| (a in [91,269]); lane = sample k ----
        int idx = bx - NH_BLOCKS;
        int a = 91 + (idx >> 5);
        int dgrp = idx & 31;
        int lane = t & 63, w = t >> 6;
        int d = dgrp * 8 + w;
        AngTab tb = tab[a];
        float cf = tb.cf, snf = tb.snf;
        float df = (float)d - 127.5f;
        float hx = fmaf(df, cf, 127.5f);
        float hy = fmaf(df, snf, 127.5f);

        float4 acc = make_float4(0.f, 0.f, 0.f, 0.f);
        #pragma unroll
        for (int j = 0; j < 4; ++j) {
            int k = j * 64 + lane;
            float kf = (float)k - 127.5f;
            float ixf = fmaf(-kf, snf, hx);
            float iyf = fmaf(kf, cf, hy);
            float vmin = fminf(fminf(ixf, 255.0f - ixf), fminf(iyf, 255.0f - iyf));
            if (!__any(vmin > -EPS)) continue;
            float m = (vmin >= EPS) ? 2.0f : 0.0f;
            if (fabsf(vmin) < EPS) {                       // rare exact check
                double ss = (double)(2 * k - 255);
                double rr = (double)(2 * d - 255);
                double rc = __dmul_rn(rr, tb.c), rs = __dmul_rn(rr, tb.sn);
                double ixd = __dadd_rn(__dmul_rn(__dsub_rn(rc, __dmul_rn(ss, tb.sn)), 0.5), 127.5);
                double iyd = __dadd_rn(__dmul_rn(__dadd_rn(rs, __dmul_rn(ss, tb.c)), 0.5), 127.5);
                bool v = (ixd >= 0.0) && (ixd <= 255.0) && (iyd >= 0.0) && (iyd <= 255.0);
                m = v ? 2.0f : 0.0f;
            }
            int j0 = (int)ixf; j0 = min(max(j0, 0), 254);
            int i0 = (int)iyf; i0 = min(max(i0, 0), 254);
            float fx = ixf - (float)j0;
            float fy = iyf - (float)i0;
            float gxm = (1.f - fx) * m, fxm = fx * m;
            float gy = 1.f - fy;
            tap_acc(pix2, i0, j0, gy * gxm, gy * fxm, fy * gxm, fy * fxm, acc);
        }

        #pragma unroll
        for (int off = 32; off; off >>= 1) {
            acc.x += __shfl_xor(acc.x, off);
            acc.y += __shfl_xor(acc.y, off);
            acc.z += __shfl_xor(acc.z, off);
            acc.w += __shfl_xor(acc.w, off);
        }
        if (lane == 0) part4[a * N_DET + d] = acc;        // sole writer
    }
}

// V-angles only: attenuation + detector-axis blur + transpose.
__global__ __launch_bounds__(256) void finish_v_k(const float4* __restrict__ part4,
                                                  float* __restrict__ out, W9 wt) {
    int d = threadIdx.x;
    int b = blockIdx.x / 179;
    int a = 91 + (blockIdx.x % 179);
    float4 s = part4[a * N_DET + d];
    float si = b ? s.z : s.x;
    float sa = b ? s.w : s.y;
    __shared__ float vb[N_DET];
    vb[d] = si * expf(-sa * 2.0f);
    __syncthreads();
    float acc = 0.f;
    #pragma unroll
    for (int i = -2; i <= 2; ++i) acc += wt.w[i + 2] * vb[refl(d + i, N_DET)];
    out[(b * N_DET + d) * N_ANG + a] = acc;
}

static void gauss_w(W9* wt, double sigma, int r) {
    double tmp[9];
    double s = 0.0;
    for (int i = -r; i <= r; ++i) {
        double v = exp(-0.5 * ((double)i / sigma) * ((double)i / sigma));
        tmp[i + r] = v;
        s += v;
    }
    for (int i = 0; i < 9; ++i) wt->w[i] = 0.f;
    for (int i = 0; i < 2 * r + 1; ++i) wt->w[i] = (float)(tmp[i] / s);
}

extern "C" void kernel_launch(void* const* d_in, const int* in_sizes, int n_in,
                              void* d_out, int out_size, void* d_ws, size_t ws_size,
                              hipStream_t stream) {
    const float* img = (const float*)d_in[0];
    const float* att = (const float*)d_in[1];
    float* out = (float*)d_out;

    char* ws = (char*)d_ws;
    AngTab* tab = (AngTab*)ws;                                  // 16 KiB slot
    uint4* pix2 = (uint4*)(ws + 16384);                         // 1 MiB (paired f16)
    float4* part4 = (float4*)(ws + 16384 + (1 << 20));          // 1.47 MiB (V only)

    double sqrt_log2 = sqrt(log(2.0));
    double sigma_img = 4.0 / (4.0 * sqrt_log2) / 2.0;           // ~0.60056, r=2
    double sigma_att = 4.0 / (2.0 * sqrt_log2) / 2.0;           // ~1.20112, r=4
    W9 wimg, watt;
    gauss_w(&wimg, sigma_img, 2);          // 5-tap at [0..4]
    gauss_w(&watt, sigma_att, 4);          // 9-tap

    blurpix_k<<<IMG, IMG, 0, stream>>>(img, att, pix2, tab, wimg, watt);
    proj_k<<<NH_BLOCKS + NV_BLOCKS, 512, 0, stream>>>(pix2, tab, part4, out, wimg);
    finish_v_k<<<2 * 179, N_DET, 0, stream>>>(part4, out, wimg);
}